// Round 6
// baseline (178.787 us; speedup 1.0000x reference)
//
#include <hip/hip_runtime.h>
#include <math.h>

// TwoBranchDH_SFNN: B=128, T=2048, H=512, D_IN=40, D_OUT=1
//
// R17 = R16 + three measured-residual fixes (R16: fir 64us vs 25.6us FMA
// floor; VALUBusy 51%; conflicts already at floor):
//  1) R=16 x Ls=16 @ 384 thr: window 31 dwords per 256 FMA (0.121 dw/FMA,
//     -23% LDS traffic). Ls=16 keeps A0 === 1 mod 16 for ALL lanes ->
//     phi(t)=t+(t>>4) gives fully static offsets; lane pitch 17 dwords,
//     gcd(17,32)=1 -> 2 lanes/bank (free). g: s_load both 16-lag slices
//     (wave-uniform base), per-lane cndmask select (off the LDS pipe).
//  2) T14 async staging: phase-1 global loads issued before phase-0
//     compute (statically unrolled reg arrays; no runtime indexing).
//  3) Parallel final reduce (all threads, lane-stride-1 partial reads).
// prepG unchanged (verified R14/R16).
//
// out[b,t] = sigmoid( sum_{s<192,d} g[s,d]*x[b,t-s,d] + c(t) ), f32 only.

#define B_   128
#define T_   2048
#define DIN  40
#define L_   192
#define TT   704             // 512 + 192 staged t-window
#define RSQ  747             // phi-padded row stride (dwords); phi(703)=746
#define NF4  3520            // TT*5 float4s per staging phase

__device__ float d_gT[DIN * L_];     // [d][s]
__device__ float d_c[T_];            // bias transient + bo

__device__ __forceinline__ float sigmf(float v) { return 1.f / (1.f + __expf(-v)); }

// ---------------- prepG: g (blocks 0..39) + c(t) (blocks 40..103) --------
__global__ __launch_bounds__(256) void prepG(
    const float* __restrict__ W1, const float* __restrict__ b1v,
    const float* __restrict__ W2, const float* __restrict__ b2v,
    const float* __restrict__ Wo, const float* __restrict__ bo,
    const float* __restrict__ tau_m, const float* __restrict__ tau_n1,
    const float* __restrict__ tau_n2)
{
    const int blk = blockIdx.x, tid = threadIdx.x;
    if (blk < 40) {
        __shared__ float cw[512], laG[512], lbG[512];
        const int d = blk;
        const int dm = (d < 20) ? d : d - 20;
        for (int i = 0; i < 2; ++i) {
            const int h = tid + 256 * i;
            const float a = sigmf(tau_m[h]);
            float bb = sigmf((d < 20) ? tau_n1[h] : tau_n2[h]);
            float diff = a - bb;
            if (fabsf(diff) < 1e-5f) { bb = a - 1e-5f; diff = 1e-5f; }
            const float w = (d < 20) ? W1[h * 20 + dm] : W2[h * 20 + dm];
            cw[h]  = Wo[h] * (1.f - a) * (1.f - bb) * w / diff;
            laG[h] = log2f(a);
            lbG[h] = log2f(bb);
        }
        __syncthreads();
        if (tid < 192) {
            const float fs1 = (float)(tid + 1);
            float acc = 0.f;
            for (int h = 0; h < 512; ++h)
                acc += cw[h] * (exp2f(fs1 * laG[h]) - exp2f(fs1 * lbG[h]));
            d_gT[d * L_ + tid] = acc;
        }
    } else {
        __shared__ float As[512], B1s[512], B2s[512], cst[512],
                         laC[512], lb1C[512], lb2C[512];
        __shared__ float red[8][32];
        for (int i = 0; i < 2; ++i) {
            const int h = tid + 256 * i;
            const float a = sigmf(tau_m[h]);
            float b1c = sigmf(tau_n1[h]); float d1 = a - b1c;
            if (fabsf(d1) < 1e-5f) { b1c = a - 1e-5f; d1 = 1e-5f; }
            float b2c = sigmf(tau_n2[h]); float d2 = a - b2c;
            if (fabsf(d2) < 1e-5f) { b2c = a - 1e-5f; d2 = 1e-5f; }
            const float wv = Wo[h], bb1 = b1v[h], bb2 = b2v[h];
            As[h]  = wv * (bb1 * a * (1.f - b1c) / d1 + bb2 * a * (1.f - b2c) / d2);
            B1s[h] = wv * bb1 * b1c * (1.f - a) / d1;
            B2s[h] = wv * bb2 * b2c * (1.f - a) / d2;
            cst[h] = wv * (bb1 + bb2);
            laC[h] = log2f(a); lb1C[h] = log2f(b1c); lb2C[h] = log2f(b2c);
        }
        __syncthreads();
        const int tl = tid & 31;
        const int hc = tid >> 5;
        const float ft1 = (float)((blk - 40) * 32 + tl + 1);
        float acc = 0.f;
        for (int hh = 0; hh < 64; ++hh) {
            const int h = hc * 64 + hh;
            acc += cst[h] - As[h] * exp2f(ft1 * laC[h])
                 + B1s[h] * exp2f(ft1 * lb1C[h])
                 + B2s[h] * exp2f(ft1 * lb2C[h]);
        }
        red[hc][tl] = acc;
        __syncthreads();
        if (tid < 32) {
            float s = bo[0];
#pragma unroll
            for (int c = 0; c < 8; ++c) s += red[c][tid];
            d_c[(blk - 40) * 32 + tid] = s;
        }
    }
}

// ---------------- main FIR kernel ----------------
// 512 blocks = 128 b x 4 t-tiles(512). 384 thr = 12 lg x 32 og.
// thread: outputs t0+16*og+{0..15}, lags [16*lg, 16*lg+16).
// A0 = 16*(og+11-lg)+1 (all lanes ===1 mod 16); phi(t)=t+(t>>4).
__global__ __launch_bounds__(384, 2) void fir_main(const float* __restrict__ x,
                                                   float* __restrict__ out)
{
    __shared__ __align__(16) float xw[20 * RSQ];   // 59760 B -> 2 blocks/CU

    const int blk = blockIdx.x;
    const int b   = blk >> 2;
    const int t0  = (blk & 3) << 9;
    const int tid = threadIdx.x;
    const int og  = tid & 31;
    const int lg  = tid >> 5;                      // 0..11
    const int half = lg & 1;
    const int wu  = __builtin_amdgcn_readfirstlane(tid >> 6);  // wave 0..5

    const float* __restrict__ xb = x + (size_t)b * (T_ * DIN);
    const float4* __restrict__ xf4 = (const float4*)xb;  // [t][10] f4/row

    float y[16];
#pragma unroll
    for (int r = 0; r < 16; ++r) y[r] = 0.f;

    const int K0  = og + 11 - lg;                  // >= 0
    const int AQ0 = 17 * K0 + 1;                   // phi(16*K0+1)

    // ---- issue phase-0 staging loads (cols 0..19) ----
    float4 xrA[10], xrB[10];
#pragma unroll
    for (int k = 0; k < 10; ++k) {
        const int phi = tid + 384 * k;
        const int tr = phi / 5, dq = phi - tr * 5;
        const int tg = t0 - L_ + tr;
        float4 v = make_float4(0.f, 0.f, 0.f, 0.f);
        if (phi < NF4 && tg >= 0) v = xf4[tg * 10 + dq];
        xrA[k] = v;
    }
    // ---- write phase-0 window ----
#pragma unroll
    for (int k = 0; k < 10; ++k) {
        const int phi = tid + 384 * k;
        if (phi < NF4) {
            const int tr = phi / 5, dq = phi - tr * 5;
            const int tph = tr + (tr >> 4);
            float* colp = &xw[(dq * 4) * RSQ + tph];
            colp[0]       = xrA[k].x;
            colp[RSQ]     = xrA[k].y;
            colp[2 * RSQ] = xrA[k].z;
            colp[3 * RSQ] = xrA[k].w;
        }
    }
    // ---- issue phase-1 staging loads (cols 20..39) before compute ----
#pragma unroll
    for (int k = 0; k < 10; ++k) {
        const int phi = tid + 384 * k;
        const int tr = phi / 5, dq = phi - tr * 5;
        const int tg = t0 - L_ + tr;
        float4 v = make_float4(0.f, 0.f, 0.f, 0.f);
        if (phi < NF4 && tg >= 0) v = xf4[tg * 10 + 5 + dq];
        xrB[k] = v;
    }
    __syncthreads();   // [S1] phase-0 window ready

#define ROW_FMA(DH, DL)                                                       \
    {                                                                         \
        const float* __restrict__ rowp = &xw[(DL) * RSQ + AQ0];               \
        float W[31];                                                          \
        _Pragma("unroll")                                                     \
        for (int m = 0; m < 15; ++m) W[m] = rowp[m];                          \
        _Pragma("unroll")                                                     \
        for (int m = 15; m < 31; ++m) W[m] = rowp[m + 1];                     \
        const float* __restrict__ grp =                                       \
            &d_gT[((DH) * 20 + (DL)) * L_ + 32 * wu];                         \
        _Pragma("unroll")                                                     \
        for (int jj = 0; jj < 16; ++jj) {                                     \
            const float gj = half ? grp[16 + jj] : grp[jj];                   \
            _Pragma("unroll")                                                 \
            for (int r = 0; r < 16; ++r)                                      \
                y[r] = fmaf(gj, W[r + 15 - jj], y[r]);                        \
        }                                                                     \
    }

#pragma unroll 2
    for (int dl = 0; dl < 20; ++dl) ROW_FMA(0, dl)
    __syncthreads();   // [S2] phase-0 reads done

    // ---- write phase-1 window ----
#pragma unroll
    for (int k = 0; k < 10; ++k) {
        const int phi = tid + 384 * k;
        if (phi < NF4) {
            const int tr = phi / 5, dq = phi - tr * 5;
            const int tph = tr + (tr >> 4);
            float* colp = &xw[(dq * 4) * RSQ + tph];
            colp[0]       = xrB[k].x;
            colp[RSQ]     = xrB[k].y;
            colp[2 * RSQ] = xrB[k].z;
            colp[3 * RSQ] = xrB[k].w;
        }
    }
    __syncthreads();   // [S3] phase-1 window ready

#pragma unroll 2
    for (int dl = 0; dl < 20; ++dl) ROW_FMA(1, dl)
    __syncthreads();   // [S4] phase-1 reads done; xw reusable
#undef ROW_FMA

    // ---- reduce 12 lag-slice partials per output ----
#pragma unroll
    for (int q = 0; q < 4; ++q)
        *(float4*)&xw[lg * 512 + og * 16 + 4 * q] =
            make_float4(y[4 * q], y[4 * q + 1], y[4 * q + 2], y[4 * q + 3]);
    __syncthreads();   // [S5] partials ready

#pragma unroll
    for (int pass = 0; pass < 2; ++pass) {
        const int o = tid + 384 * pass;
        if (o < 512) {
            float s = 0.f;
#pragma unroll
            for (int p = 0; p < 12; ++p) s += xw[p * 512 + o];
            out[(size_t)b * T_ + t0 + o] = sigmf(s + d_c[t0 + o]);
        }
    }
}

extern "C" void kernel_launch(void* const* d_in, const int* in_sizes, int n_in,
                              void* d_out, int out_size, void* d_ws, size_t ws_size,
                              hipStream_t stream)
{
    const float* x      = (const float*)d_in[0];
    const float* W1     = (const float*)d_in[1];
    const float* b1     = (const float*)d_in[2];
    const float* W2     = (const float*)d_in[3];
    const float* b2     = (const float*)d_in[4];
    const float* Wo     = (const float*)d_in[5];
    const float* bo     = (const float*)d_in[6];
    const float* tau_m  = (const float*)d_in[7];
    const float* tau_n1 = (const float*)d_in[8];
    const float* tau_n2 = (const float*)d_in[9];

    hipLaunchKernelGGL(prepG, dim3(104), dim3(256), 0, stream,
                       W1, b1, W2, b2, Wo, bo, tau_m, tau_n1, tau_n2);
    hipLaunchKernelGGL(fir_main, dim3(512), dim3(384), 0, stream,
                       x, (float*)d_out);
}

// Round 7
// 173.766 us; speedup vs baseline: 1.0289x; 1.0289x over previous
//
#include <hip/hip_runtime.h>
#include <math.h>

// TwoBranchDH_SFNN: B=128, T=2048, H=512, D_IN=40, D_OUT=1
//
// R18 = R16 (best: fir 64us, bench 162) + stall-hiding only. R17's 384-thr
// remap regressed (occupancy 32->15.7%, fir 84us) -> reverted entirely.
// R16 stall budget (154k cyc, 61k FMA floor, ~76k stalls) attacked by:
//  1) row-pair software pipeline: dl unrolled x2 with named Wa/Wb (LDS)
//     and ga/gb (SGPR s_loads) sets; all loads issue before first FMA
//     block -> second row's W/g latency hidden under 192 FMAs.
//  2) T14: phase-1 global loads issued before S1 (in flight across
//     barrier + phase-0 compute), written after S2.
//  3) __launch_bounds__(512,2) kept: empirical VGPR cap ~128 (R15's
//     (512,4) capped at 64 and spilled); worst case bounded spill, not
//     occupancy loss.
// Mapping/layout identical to R16: 8 lg x 64 og, 8 outputs, 24 lags,
// phi(t)=t+(t>>3), RS2=794, lane pitch 9 (2 lanes/bank, free).
//
// out[b,t] = sigmoid( sum_{s<192,d} g[s,d]*x[b,t-s,d] + c(t) ), f32 only.

#define B_   128
#define T_   2048
#define DIN  40
#define L_   192
#define TT   704             // 512 + 192 staged t-window
#define RS2  794             // phi-padded row stride (dwords)
#define NF4  3520            // TT*5 float4s per staging phase

__device__ float d_gT[DIN * L_];     // [d][s]
__device__ float d_c[T_];            // bias transient + bo

__device__ __forceinline__ float sigmf(float v) { return 1.f / (1.f + __expf(-v)); }

// ---------------- prepG: g (blocks 0..39) + c(t) (blocks 40..103) --------
// unchanged from R14/R16 (verified)
__global__ __launch_bounds__(256) void prepG(
    const float* __restrict__ W1, const float* __restrict__ b1v,
    const float* __restrict__ W2, const float* __restrict__ b2v,
    const float* __restrict__ Wo, const float* __restrict__ bo,
    const float* __restrict__ tau_m, const float* __restrict__ tau_n1,
    const float* __restrict__ tau_n2)
{
    const int blk = blockIdx.x, tid = threadIdx.x;
    if (blk < 40) {
        __shared__ float cw[512], laG[512], lbG[512];
        const int d = blk;
        const int dm = (d < 20) ? d : d - 20;
        for (int i = 0; i < 2; ++i) {
            const int h = tid + 256 * i;
            const float a = sigmf(tau_m[h]);
            float bb = sigmf((d < 20) ? tau_n1[h] : tau_n2[h]);
            float diff = a - bb;
            if (fabsf(diff) < 1e-5f) { bb = a - 1e-5f; diff = 1e-5f; }
            const float w = (d < 20) ? W1[h * 20 + dm] : W2[h * 20 + dm];
            cw[h]  = Wo[h] * (1.f - a) * (1.f - bb) * w / diff;
            laG[h] = log2f(a);
            lbG[h] = log2f(bb);
        }
        __syncthreads();
        if (tid < 192) {
            const float fs1 = (float)(tid + 1);
            float acc = 0.f;
            for (int h = 0; h < 512; ++h)
                acc += cw[h] * (exp2f(fs1 * laG[h]) - exp2f(fs1 * lbG[h]));
            d_gT[d * L_ + tid] = acc;
        }
    } else {
        __shared__ float As[512], B1s[512], B2s[512], cst[512],
                         laC[512], lb1C[512], lb2C[512];
        __shared__ float red[8][32];
        for (int i = 0; i < 2; ++i) {
            const int h = tid + 256 * i;
            const float a = sigmf(tau_m[h]);
            float b1c = sigmf(tau_n1[h]); float d1 = a - b1c;
            if (fabsf(d1) < 1e-5f) { b1c = a - 1e-5f; d1 = 1e-5f; }
            float b2c = sigmf(tau_n2[h]); float d2 = a - b2c;
            if (fabsf(d2) < 1e-5f) { b2c = a - 1e-5f; d2 = 1e-5f; }
            const float wv = Wo[h], bb1 = b1v[h], bb2 = b2v[h];
            As[h]  = wv * (bb1 * a * (1.f - b1c) / d1 + bb2 * a * (1.f - b2c) / d2);
            B1s[h] = wv * bb1 * b1c * (1.f - a) / d1;
            B2s[h] = wv * bb2 * b2c * (1.f - a) / d2;
            cst[h] = wv * (bb1 + bb2);
            laC[h] = log2f(a); lb1C[h] = log2f(b1c); lb2C[h] = log2f(b2c);
        }
        __syncthreads();
        const int tl = tid & 31;
        const int hc = tid >> 5;
        const float ft1 = (float)((blk - 40) * 32 + tl + 1);
        float acc = 0.f;
        for (int hh = 0; hh < 64; ++hh) {
            const int h = hc * 64 + hh;
            acc += cst[h] - As[h] * exp2f(ft1 * laC[h])
                 + B1s[h] * exp2f(ft1 * lb1C[h])
                 + B2s[h] * exp2f(ft1 * lb2C[h]);
        }
        red[hc][tl] = acc;
        __syncthreads();
        if (tid < 32) {
            float s = bo[0];
#pragma unroll
            for (int c = 0; c < 8; ++c) s += red[c][tid];
            d_c[(blk - 40) * 32 + tid] = s;
        }
    }
}

// ---------------- main FIR kernel ----------------
// 512 blocks = 128 b x 4 t-tiles(512). 512 thr = 8 lg x 64 og.
// thread: outputs t0+8*og+{0..7}, lags [24*lg, 24*lg+24).
__global__ __launch_bounds__(512, 2) void fir_main(const float* __restrict__ x,
                                                   float* __restrict__ out)
{
    __shared__ __align__(16) float xw[20 * RS2];   // 63520 B -> 2 blocks/CU

    const int blk = blockIdx.x;
    const int b   = blk >> 2;
    const int t0  = (blk & 3) << 9;
    const int tid = threadIdx.x;
    const int og  = tid & 63;
    const int lg  = tid >> 6;                     // == wave id (uniform)
    const int lg_u = __builtin_amdgcn_readfirstlane(lg);

    const float* __restrict__ xb = x + (size_t)b * (T_ * DIN);
    const float4* __restrict__ xf4 = (const float4*)xb;  // [t][10]

    float y[8];
#pragma unroll
    for (int r = 0; r < 8; ++r) y[r] = 0.f;

    // logical window base A0 = 8*og + 169 - 24*lg = 8K+1; phi(A0) = 9K+1
    const int K  = og + 21 - 3 * lg;
    const int AQ = 9 * K + 1;

    // staging thread->elements map (same both phases)
    int strv[7], sdq[7], stg_[7];
#pragma unroll
    for (int k = 0; k < 7; ++k) {
        const int phi = tid + 512 * k;
        strv[k] = phi / 5; sdq[k] = phi - strv[k] * 5;
        stg_[k] = t0 - L_ + strv[k];
    }

#define STG_LOAD(DST, COFF)                                                   \
    _Pragma("unroll")                                                         \
    for (int k = 0; k < 7; ++k) {                                             \
        float4 v = make_float4(0.f, 0.f, 0.f, 0.f);                           \
        if (tid + 512 * k < NF4 && stg_[k] >= 0)                              \
            v = xf4[stg_[k] * 10 + (COFF) + sdq[k]];                          \
        DST[k] = v;                                                           \
    }
#define STG_WRITE(SRC)                                                        \
    _Pragma("unroll")                                                         \
    for (int k = 0; k < 7; ++k) {                                             \
        if (tid + 512 * k < NF4) {                                            \
            const int tph = strv[k] + (strv[k] >> 3);                         \
            float* colp = &xw[(sdq[k] * 4) * RS2 + tph];                      \
            colp[0]       = SRC[k].x;                                         \
            colp[RS2]     = SRC[k].y;                                         \
            colp[2 * RS2] = SRC[k].z;                                         \
            colp[3 * RS2] = SRC[k].w;                                         \
        }                                                                     \
    }
#define LOADW(WV, DL)                                                         \
    {                                                                         \
        const float* __restrict__ rowp = &xw[(DL) * RS2 + AQ];                \
        _Pragma("unroll")                                                     \
        for (int m = 0; m < 31; ++m) WV[m] = rowp[m + ((m + 1) >> 3)];        \
    }
#define LOADG(GV, ROW)                                                        \
    {                                                                         \
        const float* __restrict__ grp = &d_gT[(ROW) * L_ + 24 * lg_u];        \
        _Pragma("unroll")                                                     \
        for (int j = 0; j < 24; ++j) GV[j] = grp[j];                          \
    }
#define FMAROW(WV, GV)                                                        \
    _Pragma("unroll")                                                         \
    for (int j = 0; j < 24; ++j) {                                            \
        const float gj = GV[j];                                               \
        _Pragma("unroll")                                                     \
        for (int r = 0; r < 8; ++r)                                           \
            y[r] = fmaf(gj, WV[r + 23 - j], y[r]);                            \
    }

    // ---- phase 0: stage cols 0..19, issue phase-1 loads early (T14) ----
    float4 xrA[7], xrB[7];
    STG_LOAD(xrA, 0)
    STG_LOAD(xrB, 5)          // in flight across S1 + phase-0 compute
    STG_WRITE(xrA)
    __syncthreads();   // [S1] phase-0 window ready

#pragma unroll 1
    for (int dl = 0; dl < 20; dl += 2) {    // row-pair software pipeline
        float Wa[31], Wb[31], ga[24], gb[24];
        LOADW(Wa, dl)     LOADG(ga, dl)
        LOADW(Wb, dl + 1) LOADG(gb, dl + 1)
        FMAROW(Wa, ga)
        FMAROW(Wb, gb)
    }
    __syncthreads();   // [S2] phase-0 reads done

    STG_WRITE(xrB)
    __syncthreads();   // [S3] phase-1 window ready

#pragma unroll 1
    for (int dl = 0; dl < 20; dl += 2) {
        float Wa[31], Wb[31], ga[24], gb[24];
        LOADW(Wa, dl)     LOADG(ga, 20 + dl)
        LOADW(Wb, dl + 1) LOADG(gb, 21 + dl)
        FMAROW(Wa, ga)
        FMAROW(Wb, gb)
    }
    __syncthreads();   // [S4] phase-1 reads done; xw reusable

#undef STG_LOAD
#undef STG_WRITE
#undef LOADW
#undef LOADG
#undef FMAROW

    // ---- reduce 8 lag-slice partials per output (R16 epilogue) ----
    if (lg > 0) {
        float* p = &xw[((lg - 1) * 64 + og) * 12];
        *(float4*)&p[0] = make_float4(y[0], y[1], y[2], y[3]);
        *(float4*)&p[4] = make_float4(y[4], y[5], y[6], y[7]);
    }
    __syncthreads();   // [S5] partials ready
    if (lg == 0) {
#pragma unroll
        for (int pw = 0; pw < 7; ++pw) {
            const float* p = &xw[(pw * 64 + og) * 12];
            float4 u0 = *(const float4*)&p[0];
            float4 u1 = *(const float4*)&p[4];
            y[0] += u0.x; y[1] += u0.y; y[2] += u0.z; y[3] += u0.w;
            y[4] += u1.x; y[5] += u1.y; y[6] += u1.z; y[7] += u1.w;
        }
        const float4 c0 = *(const float4*)&d_c[t0 + 8 * og];
        const float4 c1 = *(const float4*)&d_c[t0 + 8 * og + 4];
        float4 o0, o1;
        o0.x = sigmf(y[0] + c0.x); o0.y = sigmf(y[1] + c0.y);
        o0.z = sigmf(y[2] + c0.z); o0.w = sigmf(y[3] + c0.w);
        o1.x = sigmf(y[4] + c1.x); o1.y = sigmf(y[5] + c1.y);
        o1.z = sigmf(y[6] + c1.z); o1.w = sigmf(y[7] + c1.w);
        float* op = out + (size_t)b * T_ + t0 + 8 * og;
        *(float4*)&op[0] = o0;
        *(float4*)&op[4] = o1;
    }
}

extern "C" void kernel_launch(void* const* d_in, const int* in_sizes, int n_in,
                              void* d_out, int out_size, void* d_ws, size_t ws_size,
                              hipStream_t stream)
{
    const float* x      = (const float*)d_in[0];
    const float* W1     = (const float*)d_in[1];
    const float* b1     = (const float*)d_in[2];
    const float* W2     = (const float*)d_in[3];
    const float* b2     = (const float*)d_in[4];
    const float* Wo     = (const float*)d_in[5];
    const float* bo     = (const float*)d_in[6];
    const float* tau_m  = (const float*)d_in[7];
    const float* tau_n1 = (const float*)d_in[8];
    const float* tau_n2 = (const float*)d_in[9];

    hipLaunchKernelGGL(prepG, dim3(104), dim3(256), 0, stream,
                       W1, b1, W2, b2, Wo, bo, tau_m, tau_n1, tau_n2);
    hipLaunchKernelGGL(fir_main, dim3(512), dim3(512), 0, stream,
                       x, (float*)d_out);
}

// Round 8
// 126.128 us; speedup vs baseline: 1.4175x; 1.3777x over previous
//
#include <hip/hip_runtime.h>
#include <math.h>

// TwoBranchDH_SFNN: B=128, T=2048, H=512, D_IN=40, D_OUT=1
//
// R19: MFMA-Toeplitz FIR. R18 triggered the pre-committed pivot (VALU-path
// fir stuck at 64-79us vs 25.6us floor; MfmaUtil 0 the whole time).
// With t = tbase+16r+c and s = sigma+c:
//   out[tbase+16r+c] = sum_{sigma,d} x[tbase+16r-sigma,d] * gE[sigma+c,d]
// (c cancels in the x index, r in the g index) -> D[r,c] = A.B per
// mfma_f32_16x16x32_bf16, lane maps cross-verified against the R11 kernel.
// K = (sigma in [-16,191]) x 40d -> 260 MFMAs per 256 outputs.
//  - grid 512 = b x quarter(512 t); 8 waves = 8-way K-split x 2 tiles.
//  - LDS: x window 704 rows + zero-padded g image 228 rows, both bf16,
//    rows = 20 dwords, rows-of-16-stride mapping [res=w&15][quot=w>>4],
//    %5 granule permutation per row ((dq+row)%5) -> ~2-way banks
//    (R13-measured: un-permuted 16-row lane stride = 8-way on b128).
//  - f32 accum; x,g cvt to bf16 at staging (same exposure as R11's pass).
// prepG: g-section now writes d_g[s][d] row-major; c(t) section verbatim
// (verified R14/R16).

#define B_   128
#define T_   2048
#define DIN  40
#define L_   192
#define XROWS 704            // staged t-window rows (44*16)
#define GROWS 228            // gE rows [-16,211] (zero outside [0,192))
#define GOFFD 14080          // x-window dwords = 16*44*20
#define LDSDW (GOFFD + GROWS * 20)   // 18640 dw = 74560 B

typedef __attribute__((ext_vector_type(8))) short short8;
typedef __attribute__((ext_vector_type(4))) float f32x4;

__device__ __align__(16) float d_g[L_ * DIN];   // [s][d] row-major
__device__ float d_c[T_];                       // bias transient + bo

__device__ __forceinline__ float sigmf(float v) { return 1.f / (1.f + __expf(-v)); }
__device__ __forceinline__ int div5(int v) { return (v * 3277) >> 14; }  // exact v<16380

__device__ __forceinline__ unsigned pk2bf(float lo, float hi) {
#if defined(__has_builtin) && __has_builtin(__builtin_amdgcn_cvt_pk_bf16_f32)
    typedef __bf16 bf2_t __attribute__((ext_vector_type(2)));
    bf2_t r = __builtin_amdgcn_cvt_pk_bf16_f32(lo, hi);
    return __builtin_bit_cast(unsigned, r);
#else
    unsigned a = __float_as_uint(lo) + 0x8000u;
    unsigned b = __float_as_uint(hi) + 0x8000u;
    return __builtin_amdgcn_perm(b, a, 0x07060302);
#endif
}

// ---------------- prepG: g (blocks 0..39) + c(t) (blocks 40..103) --------
__global__ __launch_bounds__(256) void prepG(
    const float* __restrict__ W1, const float* __restrict__ b1v,
    const float* __restrict__ W2, const float* __restrict__ b2v,
    const float* __restrict__ Wo, const float* __restrict__ bo,
    const float* __restrict__ tau_m, const float* __restrict__ tau_n1,
    const float* __restrict__ tau_n2)
{
    const int blk = blockIdx.x, tid = threadIdx.x;
    if (blk < 40) {
        __shared__ float cw[512], laG[512], lbG[512];
        const int d = blk;
        const int dm = (d < 20) ? d : d - 20;
        for (int i = 0; i < 2; ++i) {
            const int h = tid + 256 * i;
            const float a = sigmf(tau_m[h]);
            float bb = sigmf((d < 20) ? tau_n1[h] : tau_n2[h]);
            float diff = a - bb;
            if (fabsf(diff) < 1e-5f) { bb = a - 1e-5f; diff = 1e-5f; }
            const float w = (d < 20) ? W1[h * 20 + dm] : W2[h * 20 + dm];
            cw[h]  = Wo[h] * (1.f - a) * (1.f - bb) * w / diff;
            laG[h] = log2f(a);
            lbG[h] = log2f(bb);
        }
        __syncthreads();
        if (tid < 192) {
            const float fs1 = (float)(tid + 1);
            float acc = 0.f;
            for (int h = 0; h < 512; ++h)
                acc += cw[h] * (exp2f(fs1 * laG[h]) - exp2f(fs1 * lbG[h]));
            d_g[tid * 40 + d] = acc;            // [s][d] row-major
        }
    } else {
        __shared__ float As[512], B1s[512], B2s[512], cst[512],
                         laC[512], lb1C[512], lb2C[512];
        __shared__ float red[8][32];
        for (int i = 0; i < 2; ++i) {
            const int h = tid + 256 * i;
            const float a = sigmf(tau_m[h]);
            float b1c = sigmf(tau_n1[h]); float d1 = a - b1c;
            if (fabsf(d1) < 1e-5f) { b1c = a - 1e-5f; d1 = 1e-5f; }
            float b2c = sigmf(tau_n2[h]); float d2 = a - b2c;
            if (fabsf(d2) < 1e-5f) { b2c = a - 1e-5f; d2 = 1e-5f; }
            const float wv = Wo[h], bb1 = b1v[h], bb2 = b2v[h];
            As[h]  = wv * (bb1 * a * (1.f - b1c) / d1 + bb2 * a * (1.f - b2c) / d2);
            B1s[h] = wv * bb1 * b1c * (1.f - a) / d1;
            B2s[h] = wv * bb2 * b2c * (1.f - a) / d2;
            cst[h] = wv * (bb1 + bb2);
            laC[h] = log2f(a); lb1C[h] = log2f(b1c); lb2C[h] = log2f(b2c);
        }
        __syncthreads();
        const int tl = tid & 31;
        const int hc = tid >> 5;
        const float ft1 = (float)((blk - 40) * 32 + tl + 1);
        float acc = 0.f;
        for (int hh = 0; hh < 64; ++hh) {
            const int h = hc * 64 + hh;
            acc += cst[h] - As[h] * exp2f(ft1 * laC[h])
                 + B1s[h] * exp2f(ft1 * lb1C[h])
                 + B2s[h] * exp2f(ft1 * lb2C[h]);
        }
        red[hc][tl] = acc;
        __syncthreads();
        if (tid < 32) {
            float s = bo[0];
#pragma unroll
            for (int c = 0; c < 8; ++c) s += red[c][tid];
            d_c[(blk - 40) * 32 + tid] = s;
        }
    }
}

// ---------------- main MFMA FIR kernel ----------------
// 512 blocks = 128 b x 4 quarters(512 t). 512 thr = 8 waves.
// wave wv: K-slice kc in [33wv, 33wv+33) of 264 (260 real + 4 zero-pad),
// both 256-output tiles (tau=0,1) share the B(g) fragment per step.
__global__ __launch_bounds__(512, 2) void fir_mfma(const float* __restrict__ x,
                                                   float* __restrict__ out)
{
    __shared__ __align__(16) unsigned int lds[LDSDW];   // 74560 B

    const int blk = blockIdx.x;
    const int b   = blk >> 2;
    const int t0  = (blk & 3) << 9;
    const int tid = threadIdx.x;
    const int lid = tid & 63;
    const int wv  = tid >> 6;
    const int rl  = lid & 15;
    const int g4  = (lid >> 4) & 3;

    const float4* __restrict__ xf4 = (const float4*)(x + (size_t)b * (T_ * DIN));
    const float4* __restrict__ gf4 = (const float4*)d_g;

    // ---- stage x window: w in [0,704), t = t0-191+w, rows [res][quot] ----
#pragma unroll
    for (int it = 0; it < 7; ++it) {
        const int i = tid + 512 * it;
        if (i < XROWS * 5) {
            const int w  = div5(i);
            const int dq = i - 5 * w;
            const int t  = t0 - 191 + w;
            float4 v0 = make_float4(0.f, 0.f, 0.f, 0.f), v1 = v0;
            if (t >= 0 && t < T_) { v0 = xf4[t * 10 + dq * 2]; v1 = xf4[t * 10 + dq * 2 + 1]; }
            const int rid = (w & 15) * 44 + (w >> 4);
            const int tsl = dq + rid;
            const int sl  = tsl - 5 * div5(tsl);          // (dq+rid)%5
            uint4 pv = { pk2bf(v0.x, v0.y), pk2bf(v0.z, v0.w),
                         pk2bf(v1.x, v1.y), pk2bf(v1.z, v1.w) };
            *(uint4*)&lds[rid * 20 + sl * 4] = pv;
        }
    }
    // ---- stage gE image: gr in [0,228), s = gr-16, zero outside ----
#pragma unroll
    for (int it = 0; it < 3; ++it) {
        const int i = tid + 512 * it;
        if (i < GROWS * 5) {
            const int gr = div5(i);
            const int dq = i - 5 * gr;
            const int s  = gr - 16;
            float4 v0 = make_float4(0.f, 0.f, 0.f, 0.f), v1 = v0;
            if (s >= 0 && s < L_) { v0 = gf4[s * 10 + dq * 2]; v1 = gf4[s * 10 + dq * 2 + 1]; }
            const int tsl = dq + gr;
            const int sl  = tsl - 5 * div5(tsl);
            uint4 pv = { pk2bf(v0.x, v0.y), pk2bf(v0.z, v0.w),
                         pk2bf(v1.x, v1.y), pk2bf(v1.z, v1.w) };
            *(uint4*)&lds[GOFFD + gr * 20 + sl * 4] = pv;
        }
    }
    __syncthreads();

    // ---- 33 MFMA steps: pair p = 4*kc+g4 -> (sq = sigma+16, db) ----
    f32x4 acc0 = { 0.f, 0.f, 0.f, 0.f };
    f32x4 acc1 = { 0.f, 0.f, 0.f, 0.f };
    const int kc0 = 33 * wv;
#pragma unroll 3
    for (int s = 0; s < 33; ++s) {
        const int p  = 4 * (kc0 + s) + g4;
        const int sq = div5(p);
        const int db = p - 5 * sq;
        // B fragment (g-side): row gr = sq + c  (c = rl)
        const int gr  = sq + rl;
        const int tb  = db + gr;
        const int slb = tb - 5 * div5(tb);
        const short8 gb = *(const short8*)&lds[GOFFD + gr * 20 + slb * 4];
        // A fragment tile0 (x-side): w = 16r + m, m = 207 - sq
        const int m   = 207 - sq;
        const int rid = (m & 15) * 44 + (m >> 4) + rl;
        const int ta  = db + rid;
        const int sa0 = ta - 5 * div5(ta);
        const short8 xa0 = *(const short8*)&lds[rid * 20 + sa0 * 4];
        // A fragment tile1: rid+16, slot advances by (16 % 5) = 1
        int sa1 = sa0 + 1; sa1 = (sa1 == 5) ? 0 : sa1;
        const short8 xa1 = *(const short8*)&lds[(rid + 16) * 20 + sa1 * 4];
        acc0 = __builtin_amdgcn_mfma_f32_16x16x32_bf16(xa0, gb, acc0, 0, 0, 0);
        acc1 = __builtin_amdgcn_mfma_f32_16x16x32_bf16(xa1, gb, acc1, 0, 0, 0);
    }

    // ---- reduce 8 K-slice partials, sigmoid, store ----
    __syncthreads();   // all LDS reads done; reuse as partial buffer
    {
        float* lf = (float*)lds;
#pragma unroll
        for (int q = 0; q < 4; ++q) {
            lf[((0 * 64 + lid) * 4 + q) * 9 + wv] = acc0[q];
            lf[((1 * 64 + lid) * 4 + q) * 9 + wv] = acc1[q];
        }
    }
    __syncthreads();
    {
        const int o   = tid;                 // 0..511 -> t = t0 + o
        const int tau = o >> 8, oin = o & 255;
        const int r   = oin >> 4, cc = oin & 15;
        const int lane = ((r >> 2) << 4) | cc;
        const int reg  = r & 3;
        const int Lx   = (tau * 64 + lane) * 4 + reg;
        const float* lf = (const float*)lds;
        float sacc = 0.f;
#pragma unroll
        for (int w2 = 0; w2 < 8; ++w2) sacc += lf[Lx * 9 + w2];
        out[(size_t)b * T_ + t0 + o] = sigmf(sacc + d_c[t0 + o]);
    }
}

extern "C" void kernel_launch(void* const* d_in, const int* in_sizes, int n_in,
                              void* d_out, int out_size, void* d_ws, size_t ws_size,
                              hipStream_t stream)
{
    const float* x      = (const float*)d_in[0];
    const float* W1     = (const float*)d_in[1];
    const float* b1     = (const float*)d_in[2];
    const float* W2     = (const float*)d_in[3];
    const float* b2     = (const float*)d_in[4];
    const float* Wo     = (const float*)d_in[5];
    const float* bo     = (const float*)d_in[6];
    const float* tau_m  = (const float*)d_in[7];
    const float* tau_n1 = (const float*)d_in[8];
    const float* tau_n2 = (const float*)d_in[9];

    hipLaunchKernelGGL(prepG, dim3(104), dim3(256), 0, stream,
                       W1, b1, W2, b2, Wo, bo, tau_m, tau_n1, tau_n2);
    hipLaunchKernelGGL(fir_mfma, dim3(512), dim3(512), 0, stream,
                       x, (float*)d_out);
}